// Round 2
// baseline (623.237 us; speedup 1.0000x reference)
//
#include <hip/hip_runtime.h>
#include <hip/hip_fp16.h>

typedef __attribute__((ext_vector_type(8))) _Float16 half8;
typedef __attribute__((ext_vector_type(4))) _Float16 half4;
typedef __attribute__((ext_vector_type(4))) float f32x4;

#define N_DIM 8192
#define D_DIM 512

// ---------------------------------------------------------------------------
// Prep: H = input * W, split into f16 hi/lo, stored TRANSPOSED [D][N]
// (k-contiguous) so GEMM B-tiles read 8 contiguous K per lane (ds_read_b128).
// ---------------------------------------------------------------------------
__global__ __launch_bounds__(256)
void prep_h(const float* __restrict__ inp, const float* __restrict__ W,
            _Float16* __restrict__ Hh, _Float16* __restrict__ Hl) {
  __shared__ float tile[64][65];  // +1 pad
  const int k0 = blockIdx.x * 64;   // over N_DIM (rows of input)
  const int n0 = blockIdx.y * 64;   // over D_DIM (cols)
  const int t = threadIdx.x;
  const int r  = t >> 4;
  const int c4 = (t & 15) << 2;
  #pragma unroll
  for (int i = 0; i < 4; ++i) {
    const int row = r + (i << 4);
    const float4 v = *reinterpret_cast<const float4*>(
        &inp[(size_t)(k0 + row) * D_DIM + n0 + c4]);
    tile[row][c4 + 0] = v.x * W[n0 + c4 + 0];
    tile[row][c4 + 1] = v.y * W[n0 + c4 + 1];
    tile[row][c4 + 2] = v.z * W[n0 + c4 + 2];
    tile[row][c4 + 3] = v.w * W[n0 + c4 + 3];
  }
  __syncthreads();
  const int n  = t >> 2;
  const int kc = (t & 3) << 4;   // 16 k-elements per thread
  half8 hv[2], lv[2];
  #pragma unroll
  for (int h = 0; h < 2; ++h) {
    #pragma unroll
    for (int j = 0; j < 8; ++j) {
      const float x = tile[kc + h * 8 + j][n];
      const _Float16 hi = (_Float16)x;
      hv[h][j] = hi;
      lv[h][j] = (_Float16)(x - (float)hi);
    }
  }
  const size_t base = (size_t)(n0 + n) * N_DIM + k0 + kc;
  *reinterpret_cast<half8*>(&Hh[base])     = hv[0];
  *reinterpret_cast<half8*>(&Hh[base + 8]) = hv[1];
  *reinterpret_cast<half8*>(&Hl[base])     = lv[0];
  *reinterpret_cast<half8*>(&Hl[base + 8]) = lv[1];
}

// ---------------------------------------------------------------------------
// Main GEMM: C = (Ah+Al)@(Hh+Hl) ~= Ah.Hh + Al.Hh + Ah.Hl  (fp32 accum MFMA)
// 128x128 tile, BK=64, 512 threads = 8 waves (2M x 4N), wave tile 64x32.
// LDS: As_hi|As_lo|Hs_hi|Hs_lo, each [128 rows][64 k] f16 (128B row stride)
// with XOR swizzle byte ^= (row&7)<<4 to kill the 32-way conflict.
// ---------------------------------------------------------------------------
__global__ __launch_bounds__(512, 2)
void gemm_split(const float* __restrict__ A, const _Float16* __restrict__ Hh,
                const _Float16* __restrict__ Hl, float* __restrict__ C) {
  __shared__ __align__(16) unsigned char lds[65536];
  const int t = threadIdx.x;
  // XCD-contiguous remap (hw round-robins blockIdx across 8 XCDs):
  // XCD x gets logical tiles [32x, 32x+32) = 8 A row-panels x 4 col-tiles,
  // consecutive on-XCD blocks sweep bcol fastest -> share the A row-panel in L2.
  const int lt   = (blockIdx.x & 7) * 32 + (blockIdx.x >> 3);
  const int brow = lt >> 2;      // 0..63
  const int bcol = lt & 3;       // 0..3
  const size_t arow0 = (size_t)brow * 128;
  const int ccol0 = bcol * 128;

  const int lane = t & 63;
  const int wave = t >> 6;
  const int wm = wave >> 2;      // 0..1
  const int wn = wave & 3;       // 0..3
  const int fr = lane & 15;      // frag row/col within 16
  const int fk = lane >> 4;      // k-group 0..3

  f32x4 acc[4][2] = {};

  // staging decomposition
  const int sar = t >> 4;          // A row group (0..31)
  const int sak = (t & 15) << 2;   // A k offset in floats
  const int shn = t >> 2;          // H col-row (0..127)
  const int shk = t & 3;           // H k-chunk

  for (int ks = 0; ks < N_DIM; ks += 64) {
    __syncthreads();               // previous compute done, buffer free
    // ---- stage A: fp32 -> f16 hi/lo, swizzled ds_write ----
    #pragma unroll
    for (int i = 0; i < 4; ++i) {
      const int row = sar + (i << 5);
      const float4 v = *reinterpret_cast<const float4*>(
          &A[(arow0 + row) * (size_t)N_DIM + ks + sak]);
      half4 hi4, lo4;
      hi4[0] = (_Float16)v.x; lo4[0] = (_Float16)(v.x - (float)hi4[0]);
      hi4[1] = (_Float16)v.y; lo4[1] = (_Float16)(v.y - (float)hi4[1]);
      hi4[2] = (_Float16)v.z; lo4[2] = (_Float16)(v.z - (float)hi4[2]);
      hi4[3] = (_Float16)v.w; lo4[3] = (_Float16)(v.w - (float)hi4[3]);
      unsigned off = ((unsigned)row << 7) + ((unsigned)sak << 1);
      off ^= (unsigned)(row & 7) << 4;
      *reinterpret_cast<half4*>(&lds[off])         = hi4;
      *reinterpret_cast<half4*>(&lds[16384 + off]) = lo4;
    }
    // ---- stage H (pre-split f16, [col][k] global) ----
    #pragma unroll
    for (int i = 0; i < 2; ++i) {
      const int kc = shk + (i << 2);
      const size_t g = (size_t)(ccol0 + shn) * N_DIM + ks + (kc << 3);
      const half8 vh = *reinterpret_cast<const half8*>(&Hh[g]);
      const half8 vl = *reinterpret_cast<const half8*>(&Hl[g]);
      unsigned off = ((unsigned)shn << 7) + ((unsigned)kc << 4);
      off ^= (unsigned)(shn & 7) << 4;
      *reinterpret_cast<half8*>(&lds[32768 + off]) = vh;
      *reinterpret_cast<half8*>(&lds[49152 + off]) = vl;
    }
    __syncthreads();
    // ---- compute: 2 k-slices x 4m x 2n x 3 terms = 48 MFMA/wave ----
    #pragma unroll
    for (int kk = 0; kk < 2; ++kk) {
      const unsigned kb = ((unsigned)kk << 6) + ((unsigned)fk << 4);
      half8 ah[4], al[4], hh[2], hl[2];
      #pragma unroll
      for (int m = 0; m < 4; ++m) {
        const int row = wm * 64 + m * 16 + fr;
        const unsigned off = (((unsigned)row << 7) + kb) ^ ((unsigned)(row & 7) << 4);
        ah[m] = *reinterpret_cast<const half8*>(&lds[off]);
        al[m] = *reinterpret_cast<const half8*>(&lds[16384 + off]);
      }
      #pragma unroll
      for (int n = 0; n < 2; ++n) {
        const int nr = wn * 32 + n * 16 + fr;
        const unsigned off = (((unsigned)nr << 7) + kb) ^ ((unsigned)(nr & 7) << 4);
        hh[n] = *reinterpret_cast<const half8*>(&lds[32768 + off]);
        hl[n] = *reinterpret_cast<const half8*>(&lds[49152 + off]);
      }
      #pragma unroll
      for (int m = 0; m < 4; ++m) {
        #pragma unroll
        for (int n = 0; n < 2; ++n) {
          acc[m][n] = __builtin_amdgcn_mfma_f32_16x16x32_f16(ah[m], hh[n], acc[m][n], 0, 0, 0);
          acc[m][n] = __builtin_amdgcn_mfma_f32_16x16x32_f16(al[m], hh[n], acc[m][n], 0, 0, 0);
          acc[m][n] = __builtin_amdgcn_mfma_f32_16x16x32_f16(ah[m], hl[n], acc[m][n], 0, 0, 0);
        }
      }
    }
  }
  // ---- epilogue: C/D layout col=lane&15, row=(lane>>4)*4+reg ----
  #pragma unroll
  for (int m = 0; m < 4; ++m) {
    #pragma unroll
    for (int n = 0; n < 2; ++n) {
      const int r = wm * 64 + m * 16 + (fk << 2);
      const int c = ccol0 + wn * 32 + n * 16 + fr;
      #pragma unroll
      for (int j = 0; j < 4; ++j)
        C[(arow0 + r + j) * D_DIM + c] = acc[m][n][j];
    }
  }
}

// ---------------------------------------------------------------------------
// Fallback (only if d_ws < 16 MB): correct-but-slow fp32 vector GEMM.
// ---------------------------------------------------------------------------
__global__ __launch_bounds__(256)
void gemm_naive(const float* __restrict__ A, const float* __restrict__ inp,
                const float* __restrict__ W, float* __restrict__ C) {
  const int row = blockIdx.x;
  const int t = threadIdx.x;
  float acc0 = 0.f, acc1 = 0.f;
  const int c0 = t, c1 = t + 256;
  for (int k = 0; k < N_DIM; ++k) {
    const float a = A[(size_t)row * N_DIM + k];
    acc0 += a * inp[(size_t)k * D_DIM + c0];
    acc1 += a * inp[(size_t)k * D_DIM + c1];
  }
  C[(size_t)row * D_DIM + c0] = acc0 * W[c0];
  C[(size_t)row * D_DIM + c1] = acc1 * W[c1];
}

extern "C" void kernel_launch(void* const* d_in, const int* in_sizes, int n_in,
                              void* d_out, int out_size, void* d_ws, size_t ws_size,
                              hipStream_t stream) {
  const float* inp = (const float*)d_in[0];   // [8192,512]
  const float* A   = (const float*)d_in[1];   // [8192,8192]
  const float* W   = (const float*)d_in[2];   // [512]
  float* out = (float*)d_out;                 // [8192,512]
  const size_t hElems = (size_t)N_DIM * D_DIM;
  if (ws_size >= hElems * 2 * sizeof(_Float16)) {   // 16 MiB for Hh + Hl
    _Float16* Hh = (_Float16*)d_ws;
    _Float16* Hl = Hh + hElems;
    prep_h<<<dim3(N_DIM / 64, D_DIM / 64), 256, 0, stream>>>(inp, W, Hh, Hl);
    gemm_split<<<256, 512, 0, stream>>>(A, Hh, Hl, out);
  } else {
    gemm_naive<<<N_DIM, 256, 0, stream>>>(A, inp, W, out);
  }
}

// Round 4
// 494.235 us; speedup vs baseline: 1.2610x; 1.2610x over previous
//
#include <hip/hip_runtime.h>
#include <hip/hip_fp16.h>

typedef __attribute__((ext_vector_type(8))) _Float16 half8;
typedef __attribute__((ext_vector_type(4))) float f32x4;

#define N_DIM 8192
#define D_DIM 512
#define NM (N_DIM * D_DIM)

// ---------------------------------------------------------------------------
// Prep: Hh[col][k] = f16(input[k][col] * W[col])   ([512][8192], k-contiguous)
// ---------------------------------------------------------------------------
__global__ __launch_bounds__(256)
void prep_h(const float* __restrict__ inp, const float* __restrict__ W,
            _Float16* __restrict__ Hh) {
  __shared__ float tile[64][65];
  const int k0 = blockIdx.x * 64, n0 = blockIdx.y * 64;
  const int t = threadIdx.x;
  const int r = t >> 4, c4 = (t & 15) << 2;
  #pragma unroll
  for (int i = 0; i < 4; ++i) {
    const int row = r + (i << 4);
    const float4 v = *reinterpret_cast<const float4*>(
        &inp[(size_t)(k0 + row) * D_DIM + n0 + c4]);
    tile[row][c4 + 0] = v.x * W[n0 + c4 + 0];
    tile[row][c4 + 1] = v.y * W[n0 + c4 + 1];
    tile[row][c4 + 2] = v.z * W[n0 + c4 + 2];
    tile[row][c4 + 3] = v.w * W[n0 + c4 + 3];
  }
  __syncthreads();
  const int n = t >> 2, kc = (t & 3) << 4;
  half8 hv[2];
  #pragma unroll
  for (int h = 0; h < 2; ++h)
    #pragma unroll
    for (int j = 0; j < 8; ++j)
      hv[h][j] = (_Float16)tile[kc + h * 8 + j][n];
  const size_t base = (size_t)(n0 + n) * N_DIM + k0 + kc;
  *reinterpret_cast<half8*>(&Hh[base])     = hv[0];
  *reinterpret_cast<half8*>(&Hh[base + 8]) = hv[1];
}

// ---------------------------------------------------------------------------
// GEMM (single-pass f16, fp32 accum): P = A @ H  (per k-slice partial).
// 128x128 tile, BK=64, 512 thr = 8 waves (2Mx4N), wave tile 64x32.
// Double-buffered LDS (2 x (A 16K + H 16K) = 64 KB), stage-early, XOR swizzle.
// grid 512 => split-K=2 (2 blocks/CU); grid 256 => full-K direct to out.
// ---------------------------------------------------------------------------
__global__ __launch_bounds__(512, 4)
void gemm_f16(const float* __restrict__ A, const _Float16* __restrict__ Hh,
              float* __restrict__ P) {
  __shared__ __align__(16) unsigned char lds[65536];
  const int t = threadIdx.x;
  const int nwg = gridDim.x;
  // XCD-contiguous bijective remap (nwg % 8 == 0)
  const int lt = (blockIdx.x & 7) * (nwg >> 3) + (blockIdx.x >> 3);
  int rest = lt, kslice = 0, nSteps = N_DIM / 64, kOff = 0;
  if (nwg == 512) { kslice = lt & 1; rest = lt >> 1; nSteps = N_DIM / 128; kOff = kslice * (N_DIM / 2); }
  const int bcol = rest & 3;        // 0..3
  const int brow = rest >> 2;       // 0..63
  const size_t arow0 = (size_t)brow * 128;
  const int ccol0 = bcol * 128;
  float* outp = P + (size_t)kslice * NM;

  const int lane = t & 63, wave = t >> 6;
  const int wm = wave >> 2, wn = wave & 3;
  const int fr = lane & 15, fk = lane >> 4;

  // staging decomposition: thread t -> row/col = t>>2, k-group = t&3 (16 elems)
  const int sRow = t >> 2;
  const int sG = t & 3;
  const float*    aPtr = A  + (arow0 + sRow) * (size_t)N_DIM + kOff + (sG << 4);
  const _Float16* hPtr = Hh + (size_t)(ccol0 + sRow) * N_DIM + kOff + (sG << 4);
  const unsigned aW0 = (((unsigned)sRow << 7) + ((unsigned)sG << 5)) ^ (((unsigned)sRow & 7) << 4);
  const unsigned aW1 = (((unsigned)sRow << 7) + ((unsigned)sG << 5) + 16) ^ (((unsigned)sRow & 7) << 4);

  f32x4 acc[4][2] = {};

  // ---- prologue: stage tile 0 into buf 0 ----
  {
    float4 av[4]; half8 hv[2];
    #pragma unroll
    for (int i = 0; i < 4; ++i) av[i] = *reinterpret_cast<const float4*>(aPtr + (i << 2));
    hv[0] = *reinterpret_cast<const half8*>(hPtr);
    hv[1] = *reinterpret_cast<const half8*>(hPtr + 8);
    half8 a0, a1;
    a0[0]=(_Float16)av[0].x; a0[1]=(_Float16)av[0].y; a0[2]=(_Float16)av[0].z; a0[3]=(_Float16)av[0].w;
    a0[4]=(_Float16)av[1].x; a0[5]=(_Float16)av[1].y; a0[6]=(_Float16)av[1].z; a0[7]=(_Float16)av[1].w;
    a1[0]=(_Float16)av[2].x; a1[1]=(_Float16)av[2].y; a1[2]=(_Float16)av[2].z; a1[3]=(_Float16)av[2].w;
    a1[4]=(_Float16)av[3].x; a1[5]=(_Float16)av[3].y; a1[6]=(_Float16)av[3].z; a1[7]=(_Float16)av[3].w;
    *reinterpret_cast<half8*>(&lds[aW0]) = a0;
    *reinterpret_cast<half8*>(&lds[aW1]) = a1;
    *reinterpret_cast<half8*>(&lds[16384 + aW0]) = hv[0];
    *reinterpret_cast<half8*>(&lds[16384 + aW1]) = hv[1];
  }
  __syncthreads();

  for (int s = 0; s < nSteps; ++s) {
    const unsigned cbase = (unsigned)(s & 1) << 15;
    const unsigned nbase = cbase ^ 32768u;
    const bool pf = (s + 1 < nSteps);
    float4 av[4]; half8 hv[2];
    if (pf) {  // issue next-tile global loads EARLY (latency hides under MFMA)
      const int ks = (s + 1) << 6;
      #pragma unroll
      for (int i = 0; i < 4; ++i) av[i] = *reinterpret_cast<const float4*>(aPtr + ks + (i << 2));
      hv[0] = *reinterpret_cast<const half8*>(hPtr + ks);
      hv[1] = *reinterpret_cast<const half8*>(hPtr + ks + 8);
    }
    // ---- compute from buf[cur]: 2 kk x 4m x 2n = 16 MFMA/wave ----
    #pragma unroll
    for (int kk = 0; kk < 2; ++kk) {
      const unsigned kb = ((unsigned)kk << 6) + ((unsigned)fk << 4);
      half8 a[4], h[2];
      #pragma unroll
      for (int m = 0; m < 4; ++m) {
        const unsigned row = (unsigned)(wm * 64 + m * 16 + fr);
        const unsigned off = ((row << 7) + kb) ^ ((row & 7) << 4);
        a[m] = *reinterpret_cast<const half8*>(&lds[cbase + off]);
      }
      #pragma unroll
      for (int n = 0; n < 2; ++n) {
        const unsigned nr = (unsigned)(wn * 32 + n * 16 + fr);
        const unsigned off = ((nr << 7) + kb) ^ ((nr & 7) << 4);
        h[n] = *reinterpret_cast<const half8*>(&lds[cbase + 16384 + off]);
      }
      #pragma unroll
      for (int m = 0; m < 4; ++m)
        #pragma unroll
        for (int n = 0; n < 2; ++n)
          acc[m][n] = __builtin_amdgcn_mfma_f32_16x16x32_f16(a[m], h[n], acc[m][n], 0, 0, 0);
    }
    if (pf) {  // convert + swizzled ds_write into buf[nxt]
      half8 a0, a1;
      a0[0]=(_Float16)av[0].x; a0[1]=(_Float16)av[0].y; a0[2]=(_Float16)av[0].z; a0[3]=(_Float16)av[0].w;
      a0[4]=(_Float16)av[1].x; a0[5]=(_Float16)av[1].y; a0[6]=(_Float16)av[1].z; a0[7]=(_Float16)av[1].w;
      a1[0]=(_Float16)av[2].x; a1[1]=(_Float16)av[2].y; a1[2]=(_Float16)av[2].z; a1[3]=(_Float16)av[2].w;
      a1[4]=(_Float16)av[3].x; a1[5]=(_Float16)av[3].y; a1[6]=(_Float16)av[3].z; a1[7]=(_Float16)av[3].w;
      *reinterpret_cast<half8*>(&lds[nbase + aW0]) = a0;
      *reinterpret_cast<half8*>(&lds[nbase + aW1]) = a1;
      *reinterpret_cast<half8*>(&lds[nbase + 16384 + aW0]) = hv[0];
      *reinterpret_cast<half8*>(&lds[nbase + 16384 + aW1]) = hv[1];
    }
    __syncthreads();
  }

  // ---- epilogue: C/D layout col=lane&15, row=(lane>>4)*4+reg ----
  #pragma unroll
  for (int m = 0; m < 4; ++m) {
    #pragma unroll
    for (int n = 0; n < 2; ++n) {
      const int r = wm * 64 + m * 16 + (fk << 2);
      const int c = ccol0 + wn * 32 + n * 16 + fr;
      #pragma unroll
      for (int j = 0; j < 4; ++j)
        outp[(arow0 + r + j) * D_DIM + c] = acc[m][n][j];
    }
  }
}

// ---------------------------------------------------------------------------
// Split-K reduction: out = P[0] + P[1]
// ---------------------------------------------------------------------------
__global__ __launch_bounds__(256)
void reduce2(const float* __restrict__ P, float* __restrict__ out) {
  const size_t i = ((size_t)blockIdx.x * 256 + threadIdx.x) << 2;
  const f32x4 a = *reinterpret_cast<const f32x4*>(&P[i]);
  const f32x4 b = *reinterpret_cast<const f32x4*>(&P[NM + i]);
  *reinterpret_cast<f32x4*>(&out[i]) = a + b;
}

// ---------------------------------------------------------------------------
// Fallback: correct-but-slow fp32 vector GEMM.
// ---------------------------------------------------------------------------
__global__ __launch_bounds__(256)
void gemm_naive(const float* __restrict__ A, const float* __restrict__ inp,
                const float* __restrict__ W, float* __restrict__ C) {
  const int row = blockIdx.x;
  const int t = threadIdx.x;
  float acc0 = 0.f, acc1 = 0.f;
  const int c0 = t, c1 = t + 256;
  for (int k = 0; k < N_DIM; ++k) {
    const float a = A[(size_t)row * N_DIM + k];
    acc0 += a * inp[(size_t)k * D_DIM + c0];
    acc1 += a * inp[(size_t)k * D_DIM + c1];
  }
  C[(size_t)row * D_DIM + c0] = acc0 * W[c0];
  C[(size_t)row * D_DIM + c1] = acc1 * W[c1];
}

extern "C" void kernel_launch(void* const* d_in, const int* in_sizes, int n_in,
                              void* d_out, int out_size, void* d_ws, size_t ws_size,
                              hipStream_t stream) {
  const float* inp = (const float*)d_in[0];   // [8192,512]
  const float* A   = (const float*)d_in[1];   // [8192,8192]
  const float* W   = (const float*)d_in[2];   // [512]
  float* out = (float*)d_out;                 // [8192,512]
  const size_t hBytes = (size_t)NM * sizeof(_Float16);      // 8 MiB
  const size_t pBytes = 2ull * NM * sizeof(float);          // 32 MiB
  if (ws_size >= hBytes + pBytes) {
    _Float16* Hh = (_Float16*)d_ws;
    float* P = (float*)((char*)d_ws + hBytes);
    prep_h<<<dim3(N_DIM / 64, D_DIM / 64), 256, 0, stream>>>(inp, W, Hh);
    gemm_f16<<<512, 512, 0, stream>>>(A, Hh, P);
    reduce2<<<NM / 1024, 256, 0, stream>>>(P, out);
  } else if (ws_size >= hBytes) {
    _Float16* Hh = (_Float16*)d_ws;
    prep_h<<<dim3(N_DIM / 64, D_DIM / 64), 256, 0, stream>>>(inp, W, Hh);
    gemm_f16<<<256, 512, 0, stream>>>(A, Hh, out);
  } else {
    gemm_naive<<<N_DIM, 256, 0, stream>>>(A, inp, W, out);
  }
}

// Round 7
// 466.356 us; speedup vs baseline: 1.3364x; 1.0598x over previous
//
#include <hip/hip_runtime.h>
#include <hip/hip_fp16.h>

typedef __attribute__((ext_vector_type(8))) _Float16 half8;
typedef __attribute__((ext_vector_type(4))) float f32x4;

#define N_DIM 8192
#define D_DIM 512
#define NM (N_DIM * D_DIM)

// ---------------------------------------------------------------------------
// Prep: Hh[col][k] = f16(input[k][col] * W[col])   ([512][8192], k-contiguous)
// ---------------------------------------------------------------------------
__global__ __launch_bounds__(256)
void prep_h(const float* __restrict__ inp, const float* __restrict__ W,
            _Float16* __restrict__ Hh) {
  __shared__ float tile[64][65];
  const int k0 = blockIdx.x * 64, n0 = blockIdx.y * 64;
  const int t = threadIdx.x;
  const int r = t >> 4, c4 = (t & 15) << 2;
  #pragma unroll
  for (int i = 0; i < 4; ++i) {
    const int row = r + (i << 4);
    const float4 v = *reinterpret_cast<const float4*>(
        &inp[(size_t)(k0 + row) * D_DIM + n0 + c4]);
    tile[row][c4 + 0] = v.x * W[n0 + c4 + 0];
    tile[row][c4 + 1] = v.y * W[n0 + c4 + 1];
    tile[row][c4 + 2] = v.z * W[n0 + c4 + 2];
    tile[row][c4 + 3] = v.w * W[n0 + c4 + 3];
  }
  __syncthreads();
  const int n = t >> 2, kc = (t & 3) << 4;
  half8 hv[2];
  #pragma unroll
  for (int h = 0; h < 2; ++h)
    #pragma unroll
    for (int j = 0; j < 8; ++j)
      hv[h][j] = (_Float16)tile[kc + h * 8 + j][n];
  const size_t base = (size_t)(n0 + n) * N_DIM + k0 + kc;
  *reinterpret_cast<half8*>(&Hh[base])     = hv[0];
  *reinterpret_cast<half8*>(&Hh[base + 8]) = hv[1];
}

// ---------------------------------------------------------------------------
// GEMM: P[kslice] = A[:, kslice] @ H[kslice, :]   (f16 MFMA, fp32 accum)
// BM=BN=256, BK=64. 512 thr = 8 waves (2M x 4N), wave tile 128x64, acc 8x4.
// LDS: dbuf x (A 32K + H 32K) = 128 KB. XOR swizzle ^(row&7)<<4 both sides.
// grid = 64*SK blocks (SK = split-K factor), 1 block/CU at SK=4.
// lt = kslice(hi) | brow | bcol(lo): bcol-pairs share the A panel; each XCD
// hosts one 2MB H k-slice (fits 4MB L2).
// ---------------------------------------------------------------------------
#define COMPUTE_KK(kk, cb)                                                   \
  {                                                                          \
    const unsigned kb = ((unsigned)(kk) << 6) + ((unsigned)fk << 4);         \
    half8 a[8], h[4];                                                        \
    _Pragma("unroll")                                                        \
    for (int m = 0; m < 8; ++m) {                                            \
      const unsigned row = (unsigned)(wm * 128 + m * 16 + fr);               \
      const unsigned off = ((row << 7) + kb) ^ ((row & 7) << 4);             \
      a[m] = *reinterpret_cast<const half8*>(&lds[(cb) + off]);              \
    }                                                                        \
    _Pragma("unroll")                                                        \
    for (int n = 0; n < 4; ++n) {                                            \
      const unsigned col = (unsigned)(wn * 64 + n * 16 + fr);                \
      const unsigned off = ((col << 7) + kb) ^ ((col & 7) << 4);             \
      h[n] = *reinterpret_cast<const half8*>(&lds[(cb) + 32768 + off]);      \
    }                                                                        \
    _Pragma("unroll")                                                        \
    for (int m = 0; m < 8; ++m)                                              \
      _Pragma("unroll")                                                      \
      for (int n = 0; n < 4; ++n)                                            \
        acc[m][n] = __builtin_amdgcn_mfma_f32_16x16x32_f16(a[m], h[n],       \
                                                           acc[m][n], 0,0,0);\
  }

__global__ __launch_bounds__(512, 2)
void gemm_f16(const float* __restrict__ A, const _Float16* __restrict__ Hh,
              float* __restrict__ P) {
  __shared__ __align__(16) unsigned char lds[131072];
  const int t = threadIdx.x;
  const int nwg = gridDim.x;                 // 64 * SK, multiple of 8
  const int cpx = nwg >> 3;
  const int lt = (blockIdx.x & 7) * cpx + (blockIdx.x >> 3);  // XCD-contiguous
  const int bcol   = lt & 1;
  const int brow   = (lt >> 1) & 31;
  const int kslice = lt >> 6;
  const int SK     = nwg >> 6;
  const int nSteps = 128 / SK;               // K-slice / BK
  const int kOff   = kslice * (N_DIM / SK);

  float* outp = P + (size_t)kslice * NM;
  const size_t arow0 = (size_t)brow * 256;
  const int ccol0 = bcol * 256;

  const int lane = t & 63, wave = t >> 6;
  const int wm = wave >> 2, wn = wave & 3;   // 2M x 4N wave grid
  const int fr = lane & 15, fk = lane >> 4;

  // staging: thread t -> row/col = t>>1, 32-elem k-half = t&1
  const int sRow = t >> 1, sG = t & 1;
  const float*    aPtr = A  + (arow0 + sRow) * (size_t)N_DIM + kOff + sG * 32;
  const _Float16* hPtr = Hh + (size_t)(ccol0 + sRow) * N_DIM + kOff + sG * 32;
  unsigned wA[4], wH[4];
  #pragma unroll
  for (int j = 0; j < 4; ++j) {
    unsigned off = ((unsigned)sRow << 7) + (unsigned)(sG * 64 + j * 16);
    off ^= ((unsigned)sRow & 7) << 4;
    wA[j] = off;
    wH[j] = off + 32768;
  }

  f32x4 acc[8][4] = {};

  // ---- prologue: stage tile 0 into buf 0 ----
  {
    float4 av[8]; half8 hv[4];
    #pragma unroll
    for (int j = 0; j < 8; ++j)
      av[j] = *reinterpret_cast<const float4*>(aPtr + j * 4);
    #pragma unroll
    for (int j = 0; j < 4; ++j)
      hv[j] = *reinterpret_cast<const half8*>(hPtr + j * 8);
    #pragma unroll
    for (int j = 0; j < 4; ++j) {
      const float4 u = av[2 * j], v = av[2 * j + 1];
      half8 ac;
      ac[0]=(_Float16)u.x; ac[1]=(_Float16)u.y; ac[2]=(_Float16)u.z; ac[3]=(_Float16)u.w;
      ac[4]=(_Float16)v.x; ac[5]=(_Float16)v.y; ac[6]=(_Float16)v.z; ac[7]=(_Float16)v.w;
      *reinterpret_cast<half8*>(&lds[wA[j]]) = ac;
      *reinterpret_cast<half8*>(&lds[wH[j]]) = hv[j];
    }
  }
  __syncthreads();

  for (int s = 0; s < nSteps; ++s) {
    const unsigned cb = (unsigned)(s & 1) << 16;
    const unsigned nb = cb ^ 65536u;
    const bool pf = (s + 1 < nSteps);
    float4 av[8]; half8 hv[4];
    if (pf) {  // issue next-tile loads EARLY; latency hides under kk0 compute
      const int ke = (s + 1) << 6;
      #pragma unroll
      for (int j = 0; j < 8; ++j)
        av[j] = *reinterpret_cast<const float4*>(aPtr + ke + j * 4);
      #pragma unroll
      for (int j = 0; j < 4; ++j)
        hv[j] = *reinterpret_cast<const half8*>(hPtr + ke + j * 8);
    }
    COMPUTE_KK(0, cb)
    if (pf) {  // convert + swizzled ds_write into buf[next]
      #pragma unroll
      for (int j = 0; j < 4; ++j) {
        const float4 u = av[2 * j], v = av[2 * j + 1];
        half8 ac;
        ac[0]=(_Float16)u.x; ac[1]=(_Float16)u.y; ac[2]=(_Float16)u.z; ac[3]=(_Float16)u.w;
        ac[4]=(_Float16)v.x; ac[5]=(_Float16)v.y; ac[6]=(_Float16)v.z; ac[7]=(_Float16)v.w;
        *reinterpret_cast<half8*>(&lds[nb + wA[j]]) = ac;
        *reinterpret_cast<half8*>(&lds[nb + wH[j]]) = hv[j];
      }
    }
    COMPUTE_KK(1, cb)
    __syncthreads();
  }

  // ---- epilogue: C/D layout col=lane&15, row=(lane>>4)*4+reg ----
  #pragma unroll
  for (int m = 0; m < 8; ++m) {
    #pragma unroll
    for (int n = 0; n < 4; ++n) {
      const int r = wm * 128 + m * 16 + (fk << 2);
      const int c = ccol0 + wn * 64 + n * 16 + fr;
      #pragma unroll
      for (int j = 0; j < 4; ++j)
        outp[(arow0 + r + j) * D_DIM + c] = acc[m][n][j];
    }
  }
}

// ---------------------------------------------------------------------------
// Split-K reduction: out = sum_s P[s]
// ---------------------------------------------------------------------------
__global__ __launch_bounds__(256)
void reduce_k(const float* __restrict__ P, float* __restrict__ out, int SK) {
  const size_t i = ((size_t)blockIdx.x * 256 + threadIdx.x) << 2;
  f32x4 a = *reinterpret_cast<const f32x4*>(&P[i]);
  for (int s = 1; s < SK; ++s)
    a += *reinterpret_cast<const f32x4*>(&P[(size_t)s * NM + i]);
  *reinterpret_cast<f32x4*>(&out[i]) = a;
}

// ---------------------------------------------------------------------------
// Fallback: correct-but-slow fp32 vector GEMM.
// ---------------------------------------------------------------------------
__global__ __launch_bounds__(256)
void gemm_naive(const float* __restrict__ A, const float* __restrict__ inp,
                const float* __restrict__ W, float* __restrict__ C) {
  const int row = blockIdx.x;
  const int t = threadIdx.x;
  float acc0 = 0.f, acc1 = 0.f;
  const int c0 = t, c1 = t + 256;
  for (int k = 0; k < N_DIM; ++k) {
    const float a = A[(size_t)row * N_DIM + k];
    acc0 += a * inp[(size_t)k * D_DIM + c0];
    acc1 += a * inp[(size_t)k * D_DIM + c1];
  }
  C[(size_t)row * D_DIM + c0] = acc0 * W[c0];
  C[(size_t)row * D_DIM + c1] = acc1 * W[c1];
}

extern "C" void kernel_launch(void* const* d_in, const int* in_sizes, int n_in,
                              void* d_out, int out_size, void* d_ws, size_t ws_size,
                              hipStream_t stream) {
  const float* inp = (const float*)d_in[0];   // [8192,512]
  const float* A   = (const float*)d_in[1];   // [8192,8192]
  const float* W   = (const float*)d_in[2];   // [512]
  float* out = (float*)d_out;                 // [8192,512]
  const size_t hBytes = (size_t)NM * sizeof(_Float16);      // 8 MiB
  const size_t sliceB = (size_t)NM * sizeof(float);         // 16 MiB

  if (ws_size < hBytes) {
    gemm_naive<<<N_DIM, 256, 0, stream>>>(A, inp, W, out);
    return;
  }
  _Float16* Hh = (_Float16*)d_ws;
  float* P = (float*)((char*)d_ws + hBytes);
  int SK = 1;
  if (ws_size >= hBytes + 4 * sliceB) SK = 4;        // 72 MiB
  else if (ws_size >= hBytes + 2 * sliceB) SK = 2;   // 40 MiB

  prep_h<<<dim3(N_DIM / 64, D_DIM / 64), 256, 0, stream>>>(inp, W, Hh);
  if (SK == 1) {
    gemm_f16<<<64, 512, 0, stream>>>(A, Hh, out);
  } else {
    gemm_f16<<<64 * SK, 512, 0, stream>>>(A, Hh, P);
    reduce_k<<<NM / 1024, 256, 0, stream>>>(P, out, SK);
  }
}

// Round 8
// 446.328 us; speedup vs baseline: 1.3964x; 1.0449x over previous
//
#include <hip/hip_runtime.h>
#include <hip/hip_fp16.h>

typedef __attribute__((ext_vector_type(8))) _Float16 half8;
typedef __attribute__((ext_vector_type(4))) float f32x4;

#define N_DIM 8192
#define D_DIM 512
#define NM (N_DIM * D_DIM)

typedef __attribute__((address_space(1))) const unsigned int g_u32;
typedef __attribute__((address_space(3))) unsigned int l_u32;

// ---------------------------------------------------------------------------
// prep_h: H tile images. H[c][k] = input[k][c]*W[c], f16.
// Image (bcol 0..3, kstep 0..127): 128 rows(c) x 64 k, 16 KB, row stride 128B,
// XOR-swizzled: byte(hr, kb) stored at hr*128 + (kb ^ ((hr&7)<<4)).
// GEMM then stages it with fully-linear global_load_lds.
// ---------------------------------------------------------------------------
__global__ __launch_bounds__(256)
void prep_h(const float* __restrict__ inp, const float* __restrict__ W,
            unsigned char* __restrict__ Himg) {
  __shared__ float tile[64][129];
  const int bcol = blockIdx.x & 3, kstep = blockIdx.x >> 2;   // 512 blocks
  const int k0 = kstep * 64, c0 = bcol * 128;
  const int t = threadIdx.x;
  // read 64 rows x 128 cols fp32, scale by W
  const int r = t >> 2, cq = (t & 3) * 32;
  #pragma unroll
  for (int i = 0; i < 8; ++i) {
    const float4 v = *reinterpret_cast<const float4*>(
        &inp[(size_t)(k0 + r) * D_DIM + c0 + cq + i * 4]);
    const float4 w = *reinterpret_cast<const float4*>(&W[c0 + cq + i * 4]);
    tile[r][cq + i * 4 + 0] = v.x * w.x;
    tile[r][cq + i * 4 + 1] = v.y * w.y;
    tile[r][cq + i * 4 + 2] = v.z * w.z;
    tile[r][cq + i * 4 + 3] = v.w * w.w;
  }
  __syncthreads();
  // transpose out: thread -> (hr = col, half = k-half), write swizzled 16B chunks
  const int hr = t >> 1, half = t & 1;
  _Float16 hb[32];
  #pragma unroll
  for (int k = 0; k < 32; ++k)
    hb[k] = (_Float16)tile[half * 32 + k][hr];
  unsigned char* img = Himg + (size_t)(bcol * 128 + kstep) * 16384;
  #pragma unroll
  for (int ch = 0; ch < 4; ++ch) {
    const unsigned kb = (unsigned)(half * 64 + ch * 16);
    const unsigned dst = (unsigned)(hr * 128) + (kb ^ (((unsigned)hr & 7) << 4));
    *reinterpret_cast<half8*>(img + dst) = *reinterpret_cast<half8*>(&hb[ch * 8]);
  }
}

// ---------------------------------------------------------------------------
// gemm_g: m97-structure. 128x128 tile, BK=64, 256 thr = 4 waves (2Mx2N),
// wave tile 64x64, acc 4x4. Single-buffer LDS 48KB: A fp32 32KB (source-
// swizzled global_load_lds, ^(row&7)<<5) + H f16 16KB (pre-swizzled image).
// A converted fp32->f16 at LDS->reg. SK from gridDim (1024->4, 256->1).
// 2 barriers/step; ~3 blocks/CU hide the barrier drain (m97: 874-912 TF).
// ---------------------------------------------------------------------------
__global__ __launch_bounds__(256, 3)
void gemm_g(const float* __restrict__ A, const unsigned char* __restrict__ Himg,
            float* __restrict__ P) {
  __shared__ __align__(16) unsigned char lds[49152];
  const int t = threadIdx.x;
  const int nwg = gridDim.x;                    // 1024 (SK=4) or 256 (SK=1)
  const int SK = nwg >> 8;
  const int lt = ((int)blockIdx.x & 7) * (nwg >> 3) + ((int)blockIdx.x >> 3);
  const int kslice = lt >> 8;                   // 0..SK-1
  const int brow = (lt & 255) >> 2;             // 0..63
  const int bcol = lt & 3;                      // 0..3
  const int nSteps = 128 / SK;

  const int lane = t & 63, wave = t >> 6;
  const int wm = wave >> 1, wn = wave & 1;
  const int fr = lane & 15, fk = lane >> 4;

  const float* aBase = A + ((size_t)brow * 128) * N_DIM + (size_t)kslice * (N_DIM / SK);
  const unsigned char* hBase = Himg + (size_t)(bcol * 128 + kslice * (128 / SK)) * 16384;
  float* outp = P + (size_t)kslice * NM;

  // A-stage per-lane constants: call j covers rows wave*32+j*4 + (lane>>4)
  const int rSub = lane >> 4;                   // 0..3
  const unsigned aLaneKb = (unsigned)((lane & 15) * 16);

  f32x4 acc[4][4] = {};

  for (int s = 0; s < nSteps; ++s) {
    // ---- stage A (fp32, source-swizzled): 8 x global_load_lds per wave ----
    const float* aStep = aBase + (size_t)s * 64;
    #pragma unroll
    for (int j = 0; j < 8; ++j) {
      const int rj = wave * 32 + j * 4 + rSub;
      const unsigned kb = aLaneKb ^ (unsigned)((rj & 7) << 5);
      const unsigned char* src = (const unsigned char*)(aStep + (size_t)rj * N_DIM) + kb;
      __builtin_amdgcn_global_load_lds((g_u32*)src,
                                       (l_u32*)(lds + wave * 8192 + j * 1024),
                                       16, 0, 0);
    }
    // ---- stage H (f16 image, fully linear): 4 x global_load_lds per wave ----
    const unsigned char* hStep = hBase + (size_t)s * 16384;
    #pragma unroll
    for (int j = 0; j < 4; ++j) {
      const unsigned char* src = hStep + wave * 4096 + j * 1024 + lane * 16;
      __builtin_amdgcn_global_load_lds((g_u32*)src,
                                       (l_u32*)(lds + 32768 + wave * 4096 + j * 1024),
                                       16, 0, 0);
    }
    __syncthreads();   // drains vmcnt+lgkm, barrier
    // ---- compute ----
    #pragma unroll
    for (int kk = 0; kk < 2; ++kk) {
      half8 a[4], h[4];
      #pragma unroll
      for (int m = 0; m < 4; ++m) {
        const unsigned row = (unsigned)(wm * 64 + m * 16 + fr);
        const unsigned kb0 = ((unsigned)(kk * 128 + fk * 32)) ^ ((row & 7) << 5);
        const f32x4 lo = *reinterpret_cast<const f32x4*>(lds + row * 256 + kb0);
        const f32x4 hi = *reinterpret_cast<const f32x4*>(lds + row * 256 + kb0 + 16);
        half8 v;
        v[0]=(_Float16)lo.x; v[1]=(_Float16)lo.y; v[2]=(_Float16)lo.z; v[3]=(_Float16)lo.w;
        v[4]=(_Float16)hi.x; v[5]=(_Float16)hi.y; v[6]=(_Float16)hi.z; v[7]=(_Float16)hi.w;
        a[m] = v;
      }
      #pragma unroll
      for (int n = 0; n < 4; ++n) {
        const unsigned hr = (unsigned)(wn * 64 + n * 16 + fr);
        const unsigned kb = ((unsigned)(kk * 64 + fk * 16)) ^ ((hr & 7) << 4);
        h[n] = *reinterpret_cast<const half8*>(lds + 32768 + hr * 128 + kb);
      }
      #pragma unroll
      for (int m = 0; m < 4; ++m)
        #pragma unroll
        for (int n = 0; n < 4; ++n)
          acc[m][n] = __builtin_amdgcn_mfma_f32_16x16x32_f16(a[m], h[n], acc[m][n], 0, 0, 0);
    }
    __syncthreads();   // protect LDS from next step's stage
  }

  // ---- epilogue: C/D layout col=lane&15, row=(lane>>4)*4+reg ----
  #pragma unroll
  for (int m = 0; m < 4; ++m) {
    #pragma unroll
    for (int n = 0; n < 4; ++n) {
      const int r = wm * 64 + m * 16 + (fk << 2);
      const int c = bcol * 128 + wn * 64 + n * 16 + fr;
      #pragma unroll
      for (int j = 0; j < 4; ++j)
        outp[((size_t)brow * 128 + r + j) * D_DIM + c] = acc[m][n][j];
    }
  }
}

// ---------------------------------------------------------------------------
// Split-K reduction: out = sum_s P[s]
// ---------------------------------------------------------------------------
__global__ __launch_bounds__(256)
void reduce_k(const float* __restrict__ P, float* __restrict__ out, int SK) {
  const size_t i = ((size_t)blockIdx.x * 256 + threadIdx.x) << 2;
  f32x4 a = *reinterpret_cast<const f32x4*>(&P[i]);
  for (int s = 1; s < SK; ++s)
    a += *reinterpret_cast<const f32x4*>(&P[(size_t)s * NM + i]);
  *reinterpret_cast<f32x4*>(&out[i]) = a;
}

// ---------------------------------------------------------------------------
// Fallback: correct-but-slow fp32 vector GEMM.
// ---------------------------------------------------------------------------
__global__ __launch_bounds__(256)
void gemm_naive(const float* __restrict__ A, const float* __restrict__ inp,
                const float* __restrict__ W, float* __restrict__ C) {
  const int row = blockIdx.x;
  const int t = threadIdx.x;
  float acc0 = 0.f, acc1 = 0.f;
  const int c0 = t, c1 = t + 256;
  for (int k = 0; k < N_DIM; ++k) {
    const float a = A[(size_t)row * N_DIM + k];
    acc0 += a * inp[(size_t)k * D_DIM + c0];
    acc1 += a * inp[(size_t)k * D_DIM + c1];
  }
  C[(size_t)row * D_DIM + c0] = acc0 * W[c0];
  C[(size_t)row * D_DIM + c1] = acc1 * W[c1];
}

extern "C" void kernel_launch(void* const* d_in, const int* in_sizes, int n_in,
                              void* d_out, int out_size, void* d_ws, size_t ws_size,
                              hipStream_t stream) {
  const float* inp = (const float*)d_in[0];   // [8192,512]
  const float* A   = (const float*)d_in[1];   // [8192,8192]
  const float* W   = (const float*)d_in[2];   // [512]
  float* out = (float*)d_out;                 // [8192,512]
  const size_t hImgB = 512ull * 16384ull;     // 8 MiB H tile images
  const size_t sliceB = (size_t)NM * sizeof(float);   // 16 MiB

  if (ws_size < hImgB) {
    gemm_naive<<<N_DIM, 256, 0, stream>>>(A, inp, W, out);
    return;
  }
  unsigned char* Himg = (unsigned char*)d_ws;
  prep_h<<<512, 256, 0, stream>>>(inp, W, Himg);
  if (ws_size >= hImgB + 4 * sliceB) {        // 72 MiB: SK=4, 3 blocks/CU
    float* P = (float*)((char*)d_ws + hImgB);
    gemm_g<<<1024, 256, 0, stream>>>(A, Himg, P);
    reduce_k<<<NM / 1024, 256, 0, stream>>>(P, out, 4);
  } else {                                    // SK=1 direct to out
    gemm_g<<<256, 256, 0, stream>>>(A, Himg, out);
  }
}